// Round 8
// baseline (298.978 us; speedup 1.0000x reference)
//
#include <hip/hip_runtime.h>
#include <hip/hip_bf16.h>
#include <hip/hip_fp16.h>
#include <math.h>

#define DEV_INLINE __device__ __forceinline__

typedef __attribute__((ext_vector_type(8))) short short8;
typedef __attribute__((ext_vector_type(8))) unsigned short ushort8v;
typedef __attribute__((ext_vector_type(4))) float f32x4;

constexpr int H = 128, W = 128, C = 128, B = 4;
constexpr int KK = 9;
constexpr int KT2 = 1184;         // 37 chunks * 32
constexpr int GP = 80;            // gBuf row pitch (bytes): bank-spread
constexpr int GHALF = 32 * GP;    // one gBuf parity = 2560 B

DEV_INLINE unsigned short f2bf(float f) {
  union { float f; unsigned u; } v; v.f = f;
  unsigned r = v.u + 0x7FFFu + ((v.u >> 16) & 1u);   // RNE
  return (unsigned short)(r >> 16);
}
DEV_INLINE float ubits(unsigned u) {
  union { unsigned u; float f; } v; v.u = u; return v.f;
}
DEV_INLINE unsigned pack2bf(float a, float b) {
  float2 t; t.x = a; t.y = b;
  __hip_bfloat162 h = __float22bfloat162_rn(t);
  union { __hip_bfloat162 h; unsigned u; } c; c.h = h;
  return c.u;
}
DEV_INLINE unsigned f2h2(float a, float b) {
  __half2 h = __floats2half2_rn(a, b);
  union { __half2 h; unsigned u; } c; c.h = h;
  return c.u;
}
DEV_INLINE float2 h2f2(unsigned u) {
  union { unsigned u; __half2 h; } c; c.u = u;
  return __half22float2(c.h);
}
// full bilinear blend of one dword (2 bf16 channels) from 4 corners
DEV_INLINE unsigned blend4(unsigned TL, unsigned TR, unsigned BL, unsigned BR,
                           float w00, float w01, float w10, float w11) {
  const float lo = w00 * ubits(TL << 16) + w01 * ubits(TR << 16)
                 + w10 * ubits(BL << 16) + w11 * ubits(BR << 16);
  const float hi = w00 * ubits(TL & 0xFFFF0000u) + w01 * ubits(TR & 0xFFFF0000u)
                 + w10 * ubits(BL & 0xFFFF0000u) + w11 * ubits(BR & 0xFFFF0000u);
  return pack2bf(lo, hi);
}
DEV_INLINE void lgkm_barrier() {
  asm volatile("s_waitcnt lgkmcnt(0)" ::: "memory");
  __builtin_amdgcn_s_barrier();
  __builtin_amdgcn_sched_barrier(0);
}

// Fused deform layer (round 8). r7: 78us, VALU 51%, no pipe saturated,
// occupancy 34% (grid 1024 = 4 blocks/CU hard cap) => latency-bound with a
// wave deficit. r4's K-split failure doesn't apply: that added waves while
// TA was saturated AND duplicated 50% of the work; TA is now fixed and this
// split duplicates nothing.
// Change: SPATIAL split to 32-position blocks -> grid 2048, 6 blocks/CU
// (launch_bounds(256,6)). Per-wave shapes shrink (ph1: 1 MFMA/chunk via
// wave->(pos-group,NT-half); ph3: acc[2][2], 4 MFMA/chunk; corners uint2
// 8B slices, 8 threads cover one 64B corner-run). Structure otherwise = r7:
// depth-2 producer pipeline, lgkm-only barriers, A-frags direct from global.
// LDS: gBuf 2x2560 (sOff overlays) + sTab 3456 = 8576 B.
template<int LAYER>
__global__ __launch_bounds__(256, 6)
void fusedL(const unsigned short* __restrict__ src,     // NHWC bf16
            const unsigned short* __restrict__ wOM,     // [37][2][64][8]
            const unsigned short* __restrict__ wS,      // [37][8][64][8]
            const float* __restrict__ bias,             // [32]
            const float* __restrict__ pA, const float* __restrict__ pB,
            const float* __restrict__ pM, const float* __restrict__ pV,
            const float* __restrict__ resid,
            unsigned short* __restrict__ outh,          // LAYER1 NHWC bf16
            float* __restrict__ outf)                   // LAYER2 NCHW fp32
{
  constexpr bool BN   = (LAYER == 1);
  constexpr int  NCH3 = BN ? 37 : 36;
  __shared__ __attribute__((aligned(16))) char smem[8576];
  char* gBuf = smem;                                     // [2][32][GP] = 5120
  float* sOff = (float*)smem;                            // [32][29] overlays
  unsigned* sTabU = (unsigned*)(smem + 5120);            // [9][32][3 dwords]

  const int tid  = threadIdx.x;
  const int lane = tid & 63;
  const int m16  = lane & 15;
  const int q    = lane >> 4;
  const int wv   = tid >> 6;

  const int raw  = blockIdx.x;                // 2048 blocks
  const int xcd  = raw & 7;
  const int slot = raw >> 3;                  // [0,256)
  const int b    = xcd >> 1;
  const int hy   = ((xcd & 1) << 6) | (slot >> 2);
  const int hx0  = (slot & 3) << 5;           // 32-wide segment
  const unsigned short* __restrict__ srcB = src + ((size_t)b << 14) * C;

  const int pgw  = wv & 1;                    // phase-1 pos-group of wave
  const int ntw  = wv >> 1;                   // phase-1 NT-half of wave
  const int pos1 = (pgw << 4) + m16;          // phase-1 consumer position
  const int ppos = tid >> 3;                  // producer position [0,32)
  const int ps8  = tid & 7;                   // producer 8B slice

  // ================= Phase 1: offset/mask conv (depth-2 producer) ==========
  f32x4 acc2 = (f32x4){0.f, 0.f, 0.f, 0.f};

  {  // chunk 0 (tap0: ky=0,kx=0, cg=0) -> gBuf[0]
    const int iy = hy - 1, ix = hx0 + ppos - 1;
    uint2 v; v.x = 0; v.y = 0;
    if (((unsigned)iy < (unsigned)H) && ((unsigned)ix < (unsigned)W))
      v = *(const uint2*)(srcB + (size_t)(iy * W + ix) * C + (ps8 << 2));
    *(uint2*)(gBuf + ppos * GP + (ps8 << 3)) = v;
  }
  uint2 pendV; pendV.x = 0; pendV.y = 0;
  {  // pend = chunk 1 source (tap0, cg1)
    const int iy = hy - 1, ix = hx0 + ppos - 1;
    if (((unsigned)iy < (unsigned)H) && ((unsigned)ix < (unsigned)W))
      pendV = *(const uint2*)(srcB + (size_t)(iy * W + ix) * C + 32 + (ps8 << 2));
  }
  short8 pa0 = *(const short8*)(wOM + ((size_t)(ntw * 64 + lane)) * 8);
  lgkm_barrier();

  #pragma unroll 2
  for (int ch = 0; ch < 36; ++ch) {
    const int p = ch & 1;
    const short8 a0 = pa0;
    if (ch + 1 < 36) {                         // weight prefetch (L1-hot)
      pa0 = *(const short8*)(wOM + ((size_t)((ch + 1) * 128 + ntw * 64 + lane)) * 8);
    }
    uint2 newV; newV.x = 0; newV.y = 0;
    if (ch + 2 < 36) {                         // producer: source for ch+2
      const int t2 = (ch + 2) >> 2, c2 = (ch + 2) & 3;
      const int ky = t2 / 3, kx = t2 - 3 * (t2 / 3);
      const int iy = hy + ky - 1;
      const int ix = hx0 + ppos + kx - 1;
      if (((unsigned)iy < (unsigned)H) && ((unsigned)ix < (unsigned)W))
        newV = *(const uint2*)(srcB + (size_t)(iy * W + ix) * C + (c2 << 5) + (ps8 << 2));
    }
    if (ch + 1 < 36)                           // write pend (chunk ch+1)
      *(uint2*)(gBuf + (p ^ 1) * GHALF + ppos * GP + (ps8 << 3)) = pendV;
    const short8 bfrg = *(const short8*)(gBuf + p * GHALF + pos1 * GP + (q << 4));
    acc2 = __builtin_amdgcn_mfma_f32_16x16x32_bf16(a0, bfrg, acc2, 0, 0, 0);
    pendV = newV;
    if (ch + 1 < 36) lgkm_barrier();
  }
  if constexpr (BN) {   // validity column chunk (register B)
    union { unsigned u[4]; short8 s; } bfr;
    float sv[8];
    #pragma unroll
    for (int j = 0; j < 8; ++j) {
      const int kj = (q << 3) + j;
      float s = 0.f;
      if (kj < KK) {
        const int ky = kj / 3, kx = kj - 3 * (kj / 3);
        const int iy = hy + ky - 1, ix = hx0 + pos1 + kx - 1;
        s = (((unsigned)iy < (unsigned)H) && ((unsigned)ix < (unsigned)W)) ? 1.f : 0.f;
      }
      sv[j] = s;
    }
    #pragma unroll
    for (int t = 0; t < 4; ++t) bfr.u[t] = pack2bf(sv[2 * t], sv[2 * t + 1]);
    const short8 a36 = *(const short8*)(wOM + ((size_t)(36 * 128 + ntw * 64 + lane)) * 8);
    acc2 = __builtin_amdgcn_mfma_f32_16x16x32_bf16(a36, bfr.s, acc2, 0, 0, 0);
  }
  __syncthreads();   // gBuf reads done; sOff (overlay) may be written
  // epilogue -> sOff (col m16 -> pos1, row q*4+rg -> o within NT half)
  #pragma unroll
  for (int rg = 0; rg < 4; ++rg) {
    const int o = ntw * 16 + (q << 2) + rg;
    if (o < 27) {
      float v = acc2[rg] + bias[o];
      if (o >= 18) v = 2.f / (1.f + expf(-v));
      sOff[pos1 * 29 + o] = v;
    }
  }
  __syncthreads();

  // ================= Phase 2: bilinear table -> sTab LDS ===================
  // entry: {rowpair id, pk(w00,w01), pk(w10,w11)}, w = mv*wy*wx premultiplied
  if (tid < 32) {
    const float* myOff = sOff + tid * 29;
    #pragma unroll
    for (int tap = 0; tap < 9; ++tap) {
      const int ky = tap / 3, kx = tap - 3 * (tap / 3);
      const float oy = myOff[2 * tap];
      const float ox = myOff[2 * tap + 1];
      const float mv = myOff[18 + tap];
      const float py = (float)(hy - 1 + ky) + oy;
      const float px = (float)(hx0 + tid - 1 + kx) + ox;
      const float fy = floorf(py), fx = floorf(px);
      const float ay = py - fy, ax = px - fx;
      const int y0 = (int)fy, x0 = (int)fx;
      const int y1 = y0 + 1, x1 = x0 + 1;
      const float wyt = (1.f - ay) * (((unsigned)y0 < (unsigned)H) ? 1.f : 0.f);
      const float wyb = ay * (((unsigned)y1 < (unsigned)H) ? 1.f : 0.f);
      const int y0c = min(max(y0, 0), H - 1), y1c = min(max(y1, 0), H - 1);
      const int bx  = min(max(x0, 0), W - 2);
      float wA = 0.f, wB = 0.f;
      if (x0 == bx)          { wA = 1.f - ax; wB = ax; }
      else if (x1 == bx)     { wA = ax; }
      else if (x0 == bx + 1) { wB = 1.f - ax; }
      const int tb = (tap * 32 + tid) * 3;
      sTabU[tb + 0] = (unsigned)(y0c * W + bx) | ((unsigned)(y1c * W + bx) << 16);
      sTabU[tb + 1] = f2h2(mv * wyt * wA, mv * wyt * wB);
      sTabU[tb + 2] = f2h2(mv * wyb * wA, mv * wyb * wB);
    }
  }
  __syncthreads();   // sOff dead + sTab visible; gBuf may be overwritten

  // ================= Phase 3: deform GEMM (no LDS weights, depth-2) ========
  f32x4 acc[2][2];
  #pragma unroll
  for (int i = 0; i < 2; ++i)
    #pragma unroll
    for (int j = 0; j < 2; ++j) acc[i][j] = (f32x4){0.f, 0.f, 0.f, 0.f};

  unsigned tabId, tabW0, tabW1;      // entry for tap of the PENDING chunk
  {
    const int tb = ppos * 3;
    tabId = sTabU[tb]; tabW0 = sTabU[tb + 1]; tabW1 = sTabU[tb + 2];
  }
  {  // chunk 0: load + blend + write gBuf[0]
    const int cbn = ps8 << 2;
    const unsigned short* pT  = srcB + (size_t)(tabId & 0xFFFFu) * C + cbn;
    const unsigned short* pBm = srcB + (size_t)(tabId >> 16) * C + cbn;
    const uint2 TL = *(const uint2*)(pT),  TR = *(const uint2*)(pT + C);
    const uint2 BL = *(const uint2*)(pBm), BR = *(const uint2*)(pBm + C);
    const float2 wa = h2f2(tabW0), wb = h2f2(tabW1);
    uint2 o;
    o.x = blend4(TL.x, TR.x, BL.x, BR.x, wa.x, wa.y, wb.x, wb.y);
    o.y = blend4(TL.y, TR.y, BL.y, BR.y, wa.x, wa.y, wb.x, wb.y);
    *(uint2*)(gBuf + ppos * GP + (ps8 << 3)) = o;
  }
  uint2 pTL, pTR, pBL, pBR;
  {  // pend = corners for chunk 1 (tap0, cg1)
    const int cbn = 32 + (ps8 << 2);
    const unsigned short* pT  = srcB + (size_t)(tabId & 0xFFFFu) * C + cbn;
    const unsigned short* pBm = srcB + (size_t)(tabId >> 16) * C + cbn;
    pTL = *(const uint2*)(pT);  pTR = *(const uint2*)(pT + C);
    pBL = *(const uint2*)(pBm); pBR = *(const uint2*)(pBm + C);
  }
  // A prefetch chunk 0 (direct global, L1-hot)
  short8 pa0_, pa1_;
  {
    const unsigned short* ap = wS + ((size_t)((2 * wv) * 64 + lane)) * 8;
    pa0_ = *(const short8*)(ap);
    pa1_ = *(const short8*)(ap + 512);
  }
  lgkm_barrier();

  #pragma unroll 2
  for (int ch = 0; ch < 36; ++ch) {
    const int p = ch & 1;
    const short8 af0 = pa0_, af1 = pa1_;
    if (ch + 1 < NCH3) {                       // A prefetch next chunk
      const unsigned short* ap = wS + ((size_t)((ch + 1) * 4096)) +
                                 ((size_t)((2 * wv) * 64 + lane)) * 8;
      pa0_ = *(const short8*)(ap);
      pa1_ = *(const short8*)(ap + 512);
    }
    // tab entry for chunk ch+2's tap
    unsigned ntId = tabId, ntW0 = tabW0, ntW1 = tabW1;
    if ((((ch + 2) & 3) == 0) && (ch + 2 < 36)) {
      const int tb = (((ch + 2) >> 2) * 32 + ppos) * 3;
      ntId = sTabU[tb]; ntW0 = sTabU[tb + 1]; ntW1 = sTabU[tb + 2];
    }
    // producer: issue corner loads for chunk ch+2
    uint2 nTL = pTL, nTR = pTR, nBL = pBL, nBR = pBR;
    if (ch + 2 < 36) {
      const int cbn = (((ch + 2) & 3) << 5) + (ps8 << 2);
      const unsigned short* pT  = srcB + (size_t)(ntId & 0xFFFFu) * C + cbn;
      const unsigned short* pBm = srcB + (size_t)(ntId >> 16) * C + cbn;
      nTL = *(const uint2*)(pT);  nTR = *(const uint2*)(pT + C);
      nBL = *(const uint2*)(pBm); nBR = *(const uint2*)(pBm + C);
    }
    // producer: blend pend (chunk ch+1) -> write gBuf[!p]
    if (ch + 1 < 36) {
      const float2 wa = h2f2(tabW0), wb = h2f2(tabW1);
      uint2 o;
      o.x = blend4(pTL.x, pTR.x, pBL.x, pBR.x, wa.x, wa.y, wb.x, wb.y);
      o.y = blend4(pTL.y, pTR.y, pBL.y, pBR.y, wa.x, wa.y, wb.x, wb.y);
      *(uint2*)(gBuf + (p ^ 1) * GHALF + ppos * GP + (ps8 << 3)) = o;
    }
    // consumer: 2 B-frags + 4 MFMA
    const char* gb = gBuf + p * GHALF;
    const short8 bf0 = *(const short8*)(gb + m16 * GP + (q << 4));
    const short8 bf1 = *(const short8*)(gb + (16 + m16) * GP + (q << 4));
    acc[0][0] = __builtin_amdgcn_mfma_f32_16x16x32_bf16(af0, bf0, acc[0][0], 0, 0, 0);
    acc[0][1] = __builtin_amdgcn_mfma_f32_16x16x32_bf16(af0, bf1, acc[0][1], 0, 0, 0);
    acc[1][0] = __builtin_amdgcn_mfma_f32_16x16x32_bf16(af1, bf0, acc[1][0], 0, 0, 0);
    acc[1][1] = __builtin_amdgcn_mfma_f32_16x16x32_bf16(af1, bf1, acc[1][1], 0, 0, 0);
    // rotate pipeline
    pTL = nTL; pTR = nTR; pBL = nBL; pBR = nBR;
    tabId = ntId; tabW0 = ntW0; tabW1 = ntW1;
    if (ch + 1 < 36) lgkm_barrier();
  }

  if constexpr (BN) {   // chunk 36: BN-shift column; B = per-tap sums (sTab)
    const short8 af0 = pa0_, af1 = pa1_;       // prefetched wS[36]
    #pragma unroll
    for (int pg = 0; pg < 2; ++pg) {
      float sv[8];
      #pragma unroll
      for (int j = 0; j < 8; ++j) {
        const int k = (q << 3) + j;
        float s = 0.f;
        if (k < KK) {
          const int tb = (k * 32 + pg * 16 + m16) * 3;
          const float2 a = h2f2(sTabU[tb + 1]);
          const float2 c = h2f2(sTabU[tb + 2]);
          s = a.x + a.y + c.x + c.y;
        }
        sv[j] = s;
      }
      union { unsigned u[4]; short8 s; } bfr;
      #pragma unroll
      for (int t = 0; t < 4; ++t) bfr.u[t] = pack2bf(sv[2 * t], sv[2 * t + 1]);
      acc[0][pg] = __builtin_amdgcn_mfma_f32_16x16x32_bf16(af0, bfr.s, acc[0][pg], 0, 0, 0);
      acc[1][pg] = __builtin_amdgcn_mfma_f32_16x16x32_bf16(af1, bfr.s, acc[1][pg], 0, 0, 0);
    }
  }

  // ---- epilogue ----
  #pragma unroll
  for (int oi = 0; oi < 2; ++oi) {
    const int ot = wv * 2 + oi;
    if constexpr (LAYER == 1) {
      const float a0 = pA[ot * 16 + (q << 2) + 0];
      const float a1 = pA[ot * 16 + (q << 2) + 1];
      const float a2 = pA[ot * 16 + (q << 2) + 2];
      const float a3 = pA[ot * 16 + (q << 2) + 3];
      #pragma unroll
      for (int pg = 0; pg < 2; ++pg) {
        const float v0 = acc[oi][pg][0], v1 = acc[oi][pg][1];
        const float v2 = acc[oi][pg][2], v3 = acc[oi][pg][3];
        uint2 st;
        st.x = pack2bf(v0 > 0.f ? v0 : a0 * v0, v1 > 0.f ? v1 : a1 * v1);
        st.y = pack2bf(v2 > 0.f ? v2 : a2 * v2, v3 > 0.f ? v3 : a3 * v3);
        const int n = (b << 14) + hy * W + hx0 + pg * 16 + m16;
        *(uint2*)(outh + (size_t)n * C + ot * 16 + (q << 2)) = st;
      }
    } else {
      #pragma unroll
      for (int rg = 0; rg < 4; ++rg) {
        const int o = ot * 16 + (q << 2) + rg;
        const float s  = pA[o] * rsqrtf(pV[o] + 1e-5f);
        const float sh = pB[o] - pM[o] * s;
        #pragma unroll
        for (int pg = 0; pg < 2; ++pg) {
          const size_t oi2 = (((size_t)(b * C + o)) << 14) + hy * W + hx0 + pg * 16 + m16;
          outf[oi2] = acc[oi][pg][rg] * s + sh + resid[oi2];
        }
      }
    }
  }
}

// NCHW fp32 -> NHWC bf16, LDS-tiled (coalesced loads AND stores)
__global__ __launch_bounds__(256, 4)
void xcvt3(const float* __restrict__ x, unsigned short* __restrict__ xb)
{
  __shared__ unsigned tile[64 * 69];
  const int b   = blockIdx.y;
  const int p0  = blockIdx.x * 64;
  const int tid = threadIdx.x;
  const int pl  = tid & 63;
  const int cg  = tid >> 6;
  const float* __restrict__ xp = x + (((size_t)(b * C) + cg * 32) << 14) + p0 + pl;
  #pragma unroll
  for (int j = 0; j < 16; ++j) {
    const float a = xp[(size_t)(2 * j) << 14];
    const float c = xp[(size_t)(2 * j + 1) << 14];
    tile[pl * 69 + cg * 16 + j] = pack2bf(a, c);
  }
  __syncthreads();
  const int pl2 = tid >> 2;
  const int cq  = tid & 3;
  unsigned* dst = (unsigned*)(xb + (((size_t)(b << 14)) + p0 + pl2) * C + cq * 32);
  #pragma unroll
  for (int k = 0; k < 16; k += 4) {
    uint4 v;
    v.x = tile[pl2 * 69 + cq * 16 + k];
    v.y = tile[pl2 * 69 + cq * 16 + k + 1];
    v.z = tile[pl2 * 69 + cq * 16 + k + 2];
    v.w = tile[pl2 * 69 + cq * 16 + k + 3];
    *(uint4*)(dst + k) = v;
  }
}

// Swizzled weights, tap-major chunks: wS[((ch*NT+ot)*64+lane)*8+j] =
// w[o=ot*16+(lane&15)][c=(ch&3)*32+(lane>>4)*8+j][tap=ch>>2] (ch<36);
// ch==36: BN-shift col (kj=(lane>>4)*8+j < 9), layer-1 only.
__global__ void prep5(const float* __restrict__ w1, const float* __restrict__ w2,
                      const float* __restrict__ ow1, const float* __restrict__ mw1,
                      const float* __restrict__ ob1, const float* __restrict__ mb1,
                      const float* __restrict__ ow2, const float* __restrict__ mw2,
                      const float* __restrict__ ob2, const float* __restrict__ mb2,
                      const float* __restrict__ g, const float* __restrict__ bb,
                      const float* __restrict__ m, const float* __restrict__ v,
                      unsigned short* __restrict__ wb1, unsigned short* __restrict__ wb2,
                      unsigned short* __restrict__ wom1, unsigned short* __restrict__ wom2,
                      float* __restrict__ bias1, float* __restrict__ bias2)
{
  const int i = blockIdx.x * 256 + threadIdx.x;
  if (i < 128 * KT2) {              // deform, NT=8
    const int j = i & 7, lane = (i >> 3) & 63, ot = (i >> 9) & 7, ch = i >> 12;
    const int o = ot * 16 + (lane & 15);
    const int qj = ((lane >> 4) << 3) + j;
    unsigned short v1 = 0, v2 = 0;
    if (ch < 36) {
      const int tap = ch >> 2;
      const int c   = ((ch & 3) << 5) + qj;
      const float s = g[c] * rsqrtf(v[c] + 1e-5f);
      v1 = f2bf(w1[(size_t)(o * 128 + c) * 9 + tap] * s);
      v2 = f2bf(w2[(size_t)(o * 128 + c) * 9 + tap]);
    } else if (qj < KK) {
      float acc = 0.f;
      for (int c = 0; c < 128; ++c) {
        const float s  = g[c] * rsqrtf(v[c] + 1e-5f);
        const float sh = bb[c] - m[c] * s;
        acc += w1[(size_t)(o * 128 + c) * 9 + qj] * sh;
      }
      v1 = f2bf(acc);
    }
    wb1[i] = v1; wb2[i] = v2;
  }
  if (i < 32 * KT2) {               // offset/mask, NT=2
    const int j = i & 7, lane = (i >> 3) & 63, ot = (i >> 9) & 1, ch = i >> 10;
    const int o = ot * 16 + (lane & 15);
    const int qj = ((lane >> 4) << 3) + j;
    unsigned short v1 = 0, v2 = 0;
    if (ch < 36) {
      const int tap = ch >> 2;
      const int c   = ((ch & 3) << 5) + qj;
      const float s = g[c] * rsqrtf(v[c] + 1e-5f);
      if (o < 18) {
        v1 = f2bf(ow1[(size_t)(o * 128 + c) * 9 + tap] * s);
        v2 = f2bf(ow2[(size_t)(o * 128 + c) * 9 + tap]);
      } else if (o < 27) {
        v1 = f2bf(mw1[(size_t)((o - 18) * 128 + c) * 9 + tap] * s);
        v2 = f2bf(mw2[(size_t)((o - 18) * 128 + c) * 9 + tap]);
      }
    } else if (qj < KK && o < 27) {
      const float* wsrc = (o < 18) ? ow1 + (size_t)o * 1152
                                   : mw1 + (size_t)(o - 18) * 1152;
      float acc = 0.f;
      for (int c = 0; c < 128; ++c) {
        const float s  = g[c] * rsqrtf(v[c] + 1e-5f);
        const float sh = bb[c] - m[c] * s;
        acc += wsrc[(size_t)c * 9 + qj] * sh;
      }
      v1 = f2bf(acc);
    }
    wom1[i] = v1; wom2[i] = v2;
  }
  if (i < 32) {
    float b1 = 0.f, b2 = 0.f;
    if (i < 18)      { b1 = ob1[i];      b2 = ob2[i]; }
    else if (i < 27) { b1 = mb1[i - 18]; b2 = mb2[i - 18]; }
    bias1[i] = b1; bias2[i] = b2;
  }
}

extern "C" void kernel_launch(void* const* d_in, const int* in_sizes, int n_in,
                              void* d_out, int out_size, void* d_ws, size_t ws_size,
                              hipStream_t stream)
{
  const float* x     = (const float*)d_in[0];
  const float* bn1g  = (const float*)d_in[1];
  const float* bn1b  = (const float*)d_in[2];
  const float* bn1m  = (const float*)d_in[3];
  const float* bn1v  = (const float*)d_in[4];
  const float* ow1   = (const float*)d_in[5];
  const float* ob1   = (const float*)d_in[6];
  const float* mw1   = (const float*)d_in[7];
  const float* mb1   = (const float*)d_in[8];
  const float* w1    = (const float*)d_in[9];
  const float* alpha = (const float*)d_in[10];
  const float* ow2   = (const float*)d_in[11];
  const float* ob2   = (const float*)d_in[12];
  const float* mw2   = (const float*)d_in[13];
  const float* mb2   = (const float*)d_in[14];
  const float* w2    = (const float*)d_in[15];
  const float* bn2g  = (const float*)d_in[16];
  const float* bn2b  = (const float*)d_in[17];
  const float* bn2m  = (const float*)d_in[18];
  const float* bn2v  = (const float*)d_in[19];
  float* out = (float*)d_out;

  char* wsp = (char*)d_ws;
  unsigned short* xbf  = (unsigned short*)(wsp);             // NHWC bf16
  unsigned short* r2bf = (unsigned short*)(wsp + 16777216);  // NHWC bf16
  unsigned short* wb1  = (unsigned short*)(wsp + 40632320);  // 303104
  unsigned short* wb2  = (unsigned short*)(wsp + 40935424);  // 303104
  unsigned short* wom1 = (unsigned short*)(wsp + 41238528);  // 75776
  unsigned short* wom2 = (unsigned short*)(wsp + 41314304);  // 75776
  float* bias1 = (float*)(wsp + 41390080);
  float* bias2 = (float*)(wsp + 41390208);

  xcvt3<<<dim3(256, 4), 256, 0, stream>>>(x, xbf);
  prep5<<<(128 * KT2 + 255) / 256, 256, 0, stream>>>(
      w1, w2, ow1, mw1, ob1, mb1, ow2, mw2, ob2, mb2,
      bn1g, bn1b, bn1m, bn1v, wb1, wb2, wom1, wom2, bias1, bias2);

  fusedL<1><<<2048, 256, 0, stream>>>(xbf, wom1, wb1, bias1, alpha,
      nullptr, nullptr, nullptr, nullptr, r2bf, nullptr);
  fusedL<2><<<2048, 256, 0, stream>>>(r2bf, wom2, wb2, bias2, bn2g,
      bn2b, bn2m, bn2v, x, nullptr, out);
}

// Round 9
// 245.852 us; speedup vs baseline: 1.2161x; 1.2161x over previous
//
#include <hip/hip_runtime.h>
#include <hip/hip_bf16.h>
#include <hip/hip_fp16.h>
#include <math.h>

#define DEV_INLINE __device__ __forceinline__

typedef __attribute__((ext_vector_type(8))) short short8;
typedef __attribute__((ext_vector_type(8))) unsigned short ushort8v;
typedef __attribute__((ext_vector_type(4))) float f32x4;

constexpr int H = 128, W = 128, C = 128, B = 4;
constexpr int KK = 9;
constexpr int KT2 = 1184;         // 37 chunks * 32
constexpr int GP = 80;            // gBuf row pitch (bytes): bank-spread
constexpr int GSLOT = 64 * GP;    // one gBuf slot = 5120 B (4 slots)

DEV_INLINE unsigned short f2bf(float f) {
  union { float f; unsigned u; } v; v.f = f;
  unsigned r = v.u + 0x7FFFu + ((v.u >> 16) & 1u);   // RNE
  return (unsigned short)(r >> 16);
}
DEV_INLINE float ubits(unsigned u) {
  union { unsigned u; float f; } v; v.u = u; return v.f;
}
DEV_INLINE unsigned pack2bf(float a, float b) {
  float2 t; t.x = a; t.y = b;
  __hip_bfloat162 h = __float22bfloat162_rn(t);
  union { __hip_bfloat162 h; unsigned u; } c; c.h = h;
  return c.u;
}
DEV_INLINE unsigned f2h2(float a, float b) {
  __half2 h = __floats2half2_rn(a, b);
  union { __half2 h; unsigned u; } c; c.h = h;
  return c.u;
}
DEV_INLINE float2 h2f2(unsigned u) {
  union { unsigned u; __half2 h; } c; c.u = u;
  return __half22float2(c.h);
}
// full bilinear blend of one dword (2 bf16 channels) from 4 corners
DEV_INLINE unsigned blend4(unsigned TL, unsigned TR, unsigned BL, unsigned BR,
                           float w00, float w01, float w10, float w11) {
  const float lo = w00 * ubits(TL << 16) + w01 * ubits(TR << 16)
                 + w10 * ubits(BL << 16) + w11 * ubits(BR << 16);
  const float hi = w00 * ubits(TL & 0xFFFF0000u) + w01 * ubits(TR & 0xFFFF0000u)
                 + w10 * ubits(BL & 0xFFFF0000u) + w11 * ubits(BR & 0xFFFF0000u);
  return pack2bf(lo, hi);
}
DEV_INLINE void lgkm_barrier() {
  asm volatile("s_waitcnt lgkmcnt(0)" ::: "memory");
  __builtin_amdgcn_s_barrier();
  __builtin_amdgcn_sched_barrier(0);
}

// Fused deform layer (round 9). r7=78us @650cy/chunk-iter; r8 (more blocks,
// half work/iter) REGRESSED to 414cy/iter x 2x iters => each barrier interval
// carries ~300-400cy fixed cost (skew+drain) independent of its work.
// Lever: WORK PER BARRIER, not TLP.
// Change vs r7: process 2 chunks per barrier interval with a 4-slot gBuf
// ring. Interval i: consume slots (2i)&3,(2i+1)&3; blend+write chunks
// 2i+2,2i+3 (corners loaded last interval, weights tB); issue corners for
// 2i+4,2i+5 (weights/id tI, refreshed at odd i for the next tap). Barriers
// 36->18 per phase. Same scheme in phase 1. Blend-before-issue keeps corner
// regs at one pair (32 VGPR). All else = r7: 64-pos blocks, grid 1024,
// direct-global A-frags, lgkm-only barriers, premultiplied fp16 weights.
// LDS: gBuf 4x5120=20480 (sOff overlays) + sTab 6912 = 27392 B.
template<int LAYER>
__global__ __launch_bounds__(256, 4)
void fusedL(const unsigned short* __restrict__ src,     // NHWC bf16
            const unsigned short* __restrict__ wOM,     // [37][2][64][8]
            const unsigned short* __restrict__ wS,      // [37][8][64][8]
            const float* __restrict__ bias,             // [32]
            const float* __restrict__ pA, const float* __restrict__ pB,
            const float* __restrict__ pM, const float* __restrict__ pV,
            const float* __restrict__ resid,
            unsigned short* __restrict__ outh,          // LAYER1 NHWC bf16
            float* __restrict__ outf)                   // LAYER2 NCHW fp32
{
  constexpr bool BN = (LAYER == 1);
  __shared__ __attribute__((aligned(16))) char smem[27392];
  char* gBuf = smem;                                     // [4][64][GP]
  float* sOff = (float*)smem;                            // [64][29] overlays
  unsigned* sTabU = (unsigned*)(smem + 20480);           // [9][64][3 dwords]

  const int tid  = threadIdx.x;
  const int lane = tid & 63;
  const int m16  = lane & 15;
  const int q    = lane >> 4;
  const int wv   = tid >> 6;

  const int raw  = blockIdx.x;                // 1024 blocks
  const int xcd  = raw & 7;
  const int slot = raw >> 3;                  // [0,128)
  const int b    = xcd >> 1;
  const int hy   = ((xcd & 1) << 6) | (slot >> 1);
  const int hx0  = (slot & 1) << 6;           // 64-wide segment
  const unsigned short* __restrict__ srcB = src + ((size_t)b << 14) * C;

  const int pos  = (wv << 4) + m16;           // consumer position
  const int ppos = tid >> 2;                  // producer position
  const int ps   = tid & 3;                   // producer 16B slice (8 ch)

  // ================= Phase 1: offset/mask conv (2 chunks/barrier) ==========
  f32x4 acc2[2];
  acc2[0] = (f32x4){0.f, 0.f, 0.f, 0.f};
  acc2[1] = (f32x4){0.f, 0.f, 0.f, 0.f};

  {  // chunks 0,1 (tap0) -> slots 0,1
    const int iy = hy - 1, ix = hx0 + ppos - 1;
    const bool ok = ((unsigned)iy < (unsigned)H) && ((unsigned)ix < (unsigned)W);
    #pragma unroll
    for (int c = 0; c < 2; ++c) {
      uint4 v; v.x = 0; v.y = 0; v.z = 0; v.w = 0;
      if (ok) v = *(const uint4*)(srcB + (size_t)(iy * W + ix) * C + (c << 5) + (ps << 3));
      *(uint4*)(gBuf + c * GSLOT + ppos * GP + (ps << 4)) = v;
    }
  }
  uint4 Q0, Q1;                               // pend: sources chunks 2,3
  Q0.x = 0; Q0.y = 0; Q0.z = 0; Q0.w = 0; Q1 = Q0;
  {
    const int iy = hy - 1, ix = hx0 + ppos - 1;   // still tap 0
    if (((unsigned)iy < (unsigned)H) && ((unsigned)ix < (unsigned)W)) {
      Q0 = *(const uint4*)(srcB + (size_t)(iy * W + ix) * C + (2 << 5) + (ps << 3));
      Q1 = *(const uint4*)(srcB + (size_t)(iy * W + ix) * C + (3 << 5) + (ps << 3));
    }
  }
  lgkm_barrier();

  #pragma unroll 2
  for (int i = 0; i < 18; ++i) {
    const int c0   = 2 * i;
    const int cons = (i & 1) ? 2 : 0;
    const int wsl  = (i & 1) ? 0 : 2;
    // weights for current chunks (L1-hot)
    const unsigned short* apA = wOM + ((size_t)(c0 * 128 + lane)) * 8;
    const unsigned short* apB = wOM + ((size_t)((c0 + 1) * 128 + lane)) * 8;
    const short8 a00 = *(const short8*)(apA);
    const short8 a01 = *(const short8*)(apA + 512);
    const short8 a10 = *(const short8*)(apB);
    const short8 a11 = *(const short8*)(apB + 512);
    // write pending pair (chunks c0+2, c0+3)
    if (c0 + 2 < 36) {
      *(uint4*)(gBuf + wsl * GSLOT + ppos * GP + (ps << 4)) = Q0;
      *(uint4*)(gBuf + (wsl + 1) * GSLOT + ppos * GP + (ps << 4)) = Q1;
    }
    // load sources for chunks c0+4, c0+5 (same tap within pair)
    if (c0 + 4 < 36) {
      const int t4 = (c0 + 4) >> 2;
      const int ky = t4 / 3, kx = t4 - 3 * (t4 / 3);
      const int iy = hy + ky - 1;
      const int ix = hx0 + ppos + kx - 1;
      const bool ok = ((unsigned)iy < (unsigned)H) && ((unsigned)ix < (unsigned)W);
      uint4 z; z.x = 0; z.y = 0; z.z = 0; z.w = 0;
      Q0 = z; Q1 = z;
      if (ok) {
        const unsigned short* sp = srcB + (size_t)(iy * W + ix) * C + (ps << 3);
        Q0 = *(const uint4*)(sp + (((c0 + 4) & 3) << 5));
        Q1 = *(const uint4*)(sp + (((c0 + 5) & 3) << 5));
      }
    }
    // consumer: 2 chunks
    const short8 bf0 = *(const short8*)(gBuf + cons * GSLOT + pos * GP + (q << 4));
    const short8 bf1 = *(const short8*)(gBuf + (cons + 1) * GSLOT + pos * GP + (q << 4));
    acc2[0] = __builtin_amdgcn_mfma_f32_16x16x32_bf16(a00, bf0, acc2[0], 0, 0, 0);
    acc2[1] = __builtin_amdgcn_mfma_f32_16x16x32_bf16(a01, bf0, acc2[1], 0, 0, 0);
    acc2[0] = __builtin_amdgcn_mfma_f32_16x16x32_bf16(a10, bf1, acc2[0], 0, 0, 0);
    acc2[1] = __builtin_amdgcn_mfma_f32_16x16x32_bf16(a11, bf1, acc2[1], 0, 0, 0);
    if (i < 17) lgkm_barrier();
  }
  if constexpr (BN) {   // validity column chunk (register B)
    union { unsigned u[4]; short8 s; } bfr;
    float sv[8];
    #pragma unroll
    for (int j = 0; j < 8; ++j) {
      const int kj = (q << 3) + j;
      float s = 0.f;
      if (kj < KK) {
        const int ky = kj / 3, kx = kj - 3 * (kj / 3);
        const int iy = hy + ky - 1, ix = hx0 + pos + kx - 1;
        s = (((unsigned)iy < (unsigned)H) && ((unsigned)ix < (unsigned)W)) ? 1.f : 0.f;
      }
      sv[j] = s;
    }
    #pragma unroll
    for (int t = 0; t < 4; ++t) bfr.u[t] = pack2bf(sv[2 * t], sv[2 * t + 1]);
    const unsigned short* ap = wOM + ((size_t)36 * 128 + lane) * 8;
    acc2[0] = __builtin_amdgcn_mfma_f32_16x16x32_bf16(*(const short8*)(ap), bfr.s, acc2[0], 0, 0, 0);
    acc2[1] = __builtin_amdgcn_mfma_f32_16x16x32_bf16(*(const short8*)(ap + 512), bfr.s, acc2[1], 0, 0, 0);
  }
  __syncthreads();   // gBuf reads done; sOff (overlay) may be written
  // epilogue -> sOff (D col = m16 -> pos, row = q*4+rg -> o)
  #pragma unroll
  for (int ot = 0; ot < 2; ++ot) {
    #pragma unroll
    for (int rg = 0; rg < 4; ++rg) {
      const int o = ot * 16 + (q << 2) + rg;
      if (o < 27) {
        float v = acc2[ot][rg] + bias[o];
        if (o >= 18) v = 2.f / (1.f + expf(-v));
        sOff[pos * 29 + o] = v;
      }
    }
  }
  __syncthreads();

  // ================= Phase 2: bilinear table -> sTab LDS ===================
  // entry: {rowpair id, pk(w00,w01), pk(w10,w11)}, w = mv*wy*wx premultiplied
  {
    const float* myOff = sOff + pos * 29;
    #pragma unroll
    for (int tap = 0; tap < 9; ++tap) {
      const int ky = tap / 3, kx = tap - 3 * (tap / 3);
      const float oy = myOff[2 * tap];
      const float ox = myOff[2 * tap + 1];
      const float mv = myOff[18 + tap];
      const float py = (float)(hy - 1 + ky) + oy;
      const float px = (float)(hx0 + pos - 1 + kx) + ox;
      const float fy = floorf(py), fx = floorf(px);
      const float ay = py - fy, ax = px - fx;
      const int y0 = (int)fy, x0 = (int)fx;
      const int y1 = y0 + 1, x1 = x0 + 1;
      const float wyt = (1.f - ay) * (((unsigned)y0 < (unsigned)H) ? 1.f : 0.f);
      const float wyb = ay * (((unsigned)y1 < (unsigned)H) ? 1.f : 0.f);
      const int y0c = min(max(y0, 0), H - 1), y1c = min(max(y1, 0), H - 1);
      const int bx  = min(max(x0, 0), W - 2);
      float wA = 0.f, wB = 0.f;
      if (x0 == bx)          { wA = 1.f - ax; wB = ax; }
      else if (x1 == bx)     { wA = ax; }
      else if (x0 == bx + 1) { wB = 1.f - ax; }
      if (q == 0) {   // one writer per pos
        const int tb = (tap * 64 + pos) * 3;
        sTabU[tb + 0] = (unsigned)(y0c * W + bx) | ((unsigned)(y1c * W + bx) << 16);
        sTabU[tb + 1] = f2h2(mv * wyt * wA, mv * wyt * wB);
        sTabU[tb + 2] = f2h2(mv * wyb * wA, mv * wyb * wB);
      }
    }
  }
  __syncthreads();   // sOff dead + sTab visible; gBuf may be overwritten

  // ================= Phase 3: deform GEMM (2 chunks/barrier, 4-slot ring) ==
  f32x4 acc[2][4];
  #pragma unroll
  for (int i = 0; i < 2; ++i)
    #pragma unroll
    for (int j = 0; j < 4; ++j) acc[i][j] = (f32x4){0.f, 0.f, 0.f, 0.f};

  unsigned tI_id, tI_w0, tI_w1;      // tab for the pair being ISSUED
  {
    const int tb = ppos * 3;
    tI_id = sTabU[tb]; tI_w0 = sTabU[tb + 1]; tI_w1 = sTabU[tb + 2];
  }
  {  // prologue: chunks 0,1 -> load+blend+write slots 0,1
    const float2 wa = h2f2(tI_w0), wb = h2f2(tI_w1);
    #pragma unroll
    for (int c = 0; c < 2; ++c) {
      const int cbn = (c << 5) + (ps << 3);
      const unsigned short* pT  = srcB + (size_t)(tI_id & 0xFFFFu) * C + cbn;
      const unsigned short* pBm = srcB + (size_t)(tI_id >> 16) * C + cbn;
      const uint4 TL = *(const uint4*)(pT),  TR = *(const uint4*)(pT + C);
      const uint4 BL = *(const uint4*)(pBm), BR = *(const uint4*)(pBm + C);
      uint4 o;
      o.x = blend4(TL.x, TR.x, BL.x, BR.x, wa.x, wa.y, wb.x, wb.y);
      o.y = blend4(TL.y, TR.y, BL.y, BR.y, wa.x, wa.y, wb.x, wb.y);
      o.z = blend4(TL.z, TR.z, BL.z, BR.z, wa.x, wa.y, wb.x, wb.y);
      o.w = blend4(TL.w, TR.w, BL.w, BR.w, wa.x, wa.y, wb.x, wb.y);
      *(uint4*)(gBuf + c * GSLOT + ppos * GP + (ps << 4)) = o;
    }
  }
  // pend: corners for chunks 2,3 (pair 1, tap 0)
  uint4 P0TL, P0TR, P0BL, P0BR, P1TL, P1TR, P1BL, P1BR;
  {
    const unsigned short* rT  = srcB + (size_t)(tI_id & 0xFFFFu) * C + (ps << 3);
    const unsigned short* rB  = srcB + (size_t)(tI_id >> 16) * C + (ps << 3);
    P0TL = *(const uint4*)(rT + 64);      P0TR = *(const uint4*)(rT + 64 + C);
    P0BL = *(const uint4*)(rB + 64);      P0BR = *(const uint4*)(rB + 64 + C);
    P1TL = *(const uint4*)(rT + 96);      P1TR = *(const uint4*)(rT + 96 + C);
    P1BL = *(const uint4*)(rB + 96);      P1BR = *(const uint4*)(rB + 96 + C);
  }
  unsigned tB_w0 = tI_w0, tB_w1 = tI_w1;   // blend-tab for pending pair
  {  // tI <- pair 2 (tap 1)
    const int tb = (64 + ppos) * 3;
    tI_id = sTabU[tb]; tI_w0 = sTabU[tb + 1]; tI_w1 = sTabU[tb + 2];
  }
  lgkm_barrier();

  #pragma unroll 2
  for (int i = 0; i < 18; ++i) {
    const int c0   = 2 * i;
    const int cons = (i & 1) ? 2 : 0;
    const int wsl  = (i & 1) ? 0 : 2;
    // A-fragments for current chunks (direct global, L1-hot)
    const unsigned short* apA = wS + (size_t)c0 * 4096 +
                                ((size_t)((2 * wv) * 64 + lane)) * 8;
    const unsigned short* apB = apA + 4096;
    const short8 afA0 = *(const short8*)(apA);
    const short8 afA1 = *(const short8*)(apA + 512);
    const short8 afB0 = *(const short8*)(apB);
    const short8 afB1 = *(const short8*)(apB + 512);
    // blend pending pair (chunks c0+2, c0+3) -> write slots
    if (c0 + 2 < 36) {
      const float2 wa = h2f2(tB_w0), wb = h2f2(tB_w1);
      uint4 o;
      o.x = blend4(P0TL.x, P0TR.x, P0BL.x, P0BR.x, wa.x, wa.y, wb.x, wb.y);
      o.y = blend4(P0TL.y, P0TR.y, P0BL.y, P0BR.y, wa.x, wa.y, wb.x, wb.y);
      o.z = blend4(P0TL.z, P0TR.z, P0BL.z, P0BR.z, wa.x, wa.y, wb.x, wb.y);
      o.w = blend4(P0TL.w, P0TR.w, P0BL.w, P0BR.w, wa.x, wa.y, wb.x, wb.y);
      *(uint4*)(gBuf + wsl * GSLOT + ppos * GP + (ps << 4)) = o;
      o.x = blend4(P1TL.x, P1TR.x, P1BL.x, P1BR.x, wa.x, wa.y, wb.x, wb.y);
      o.y = blend4(P1TL.y, P1TR.y, P1BL.y, P1BR.y, wa.x, wa.y, wb.x, wb.y);
      o.z = blend4(P1TL.z, P1TR.z, P1BL.z, P1BR.z, wa.x, wa.y, wb.x, wb.y);
      o.w = blend4(P1TL.w, P1TR.w, P1BL.w, P1BR.w, wa.x, wa.y, wb.x, wb.y);
      *(uint4*)(gBuf + (wsl + 1) * GSLOT + ppos * GP + (ps << 4)) = o;
    }
    // issue corners for chunks c0+4, c0+5 (pair i+2) with tI
    if (c0 + 4 < 36) {
      const unsigned short* rT = srcB + (size_t)(tI_id & 0xFFFFu) * C + (ps << 3);
      const unsigned short* rB = srcB + (size_t)(tI_id >> 16) * C + (ps << 3);
      const int b0 = (((c0 + 4) & 3) << 5);
      const int b1 = (((c0 + 5) & 3) << 5);
      P0TL = *(const uint4*)(rT + b0);  P0TR = *(const uint4*)(rT + b0 + C);
      P0BL = *(const uint4*)(rB + b0);  P0BR = *(const uint4*)(rB + b0 + C);
      P1TL = *(const uint4*)(rT + b1);  P1TR = *(const uint4*)(rT + b1 + C);
      P1BL = *(const uint4*)(rB + b1);  P1BR = *(const uint4*)(rB + b1 + C);
    }
    // rotate tabs: pending pair becomes the one just issued
    tB_w0 = tI_w0; tB_w1 = tI_w1;
    if ((i & 1) && (c0 + 6 < 36)) {    // pair i+3 starts a new tap
      const int tb = (((i + 3) >> 1) * 64 + ppos) * 3;
      tI_id = sTabU[tb]; tI_w0 = sTabU[tb + 1]; tI_w1 = sTabU[tb + 2];
    }
    // consumer: 2 chunks x {4 B-frags + 8 MFMA}
    const char* gbA = gBuf + cons * GSLOT;
    const char* gbB = gBuf + (cons + 1) * GSLOT;
    short8 bf[4];
    #pragma unroll
    for (int pg = 0; pg < 4; ++pg)
      bf[pg] = *(const short8*)(gbA + (pg * 16 + m16) * GP + (q << 4));
    #pragma unroll
    for (int pg = 0; pg < 4; ++pg) {
      acc[0][pg] = __builtin_amdgcn_mfma_f32_16x16x32_bf16(afA0, bf[pg], acc[0][pg], 0, 0, 0);
      acc[1][pg] = __builtin_amdgcn_mfma_f32_16x16x32_bf16(afA1, bf[pg], acc[1][pg], 0, 0, 0);
    }
    #pragma unroll
    for (int pg = 0; pg < 4; ++pg)
      bf[pg] = *(const short8*)(gbB + (pg * 16 + m16) * GP + (q << 4));
    #pragma unroll
    for (int pg = 0; pg < 4; ++pg) {
      acc[0][pg] = __builtin_amdgcn_mfma_f32_16x16x32_bf16(afB0, bf[pg], acc[0][pg], 0, 0, 0);
      acc[1][pg] = __builtin_amdgcn_mfma_f32_16x16x32_bf16(afB1, bf[pg], acc[1][pg], 0, 0, 0);
    }
    if (i < 17) lgkm_barrier();
  }

  if constexpr (BN) {   // chunk 36: BN-shift column; B = per-tap sums (sTab)
    const unsigned short* ap = wS + (size_t)36 * 4096 +
                               ((size_t)((2 * wv) * 64 + lane)) * 8;
    const short8 af0 = *(const short8*)(ap);
    const short8 af1 = *(const short8*)(ap + 512);
    #pragma unroll
    for (int pg = 0; pg < 4; ++pg) {
      float sv[8];
      #pragma unroll
      for (int j = 0; j < 8; ++j) {
        const int k = (q << 3) + j;
        float s = 0.f;
        if (k < KK) {
          const int tb = (k * 64 + pg * 16 + m16) * 3;
          const float2 a = h2f2(sTabU[tb + 1]);
          const float2 c = h2f2(sTabU[tb + 2]);
          s = a.x + a.y + c.x + c.y;
        }
        sv[j] = s;
      }
      union { unsigned u[4]; short8 s; } bfr;
      #pragma unroll
      for (int t = 0; t < 4; ++t) bfr.u[t] = pack2bf(sv[2 * t], sv[2 * t + 1]);
      acc[0][pg] = __builtin_amdgcn_mfma_f32_16x16x32_bf16(af0, bfr.s, acc[0][pg], 0, 0, 0);
      acc[1][pg] = __builtin_amdgcn_mfma_f32_16x16x32_bf16(af1, bfr.s, acc[1][pg], 0, 0, 0);
    }
  }

  // ---- epilogue ----
  #pragma unroll
  for (int oi = 0; oi < 2; ++oi) {
    const int ot = wv * 2 + oi;
    if constexpr (LAYER == 1) {
      const float a0 = pA[ot * 16 + (q << 2) + 0];
      const float a1 = pA[ot * 16 + (q << 2) + 1];
      const float a2 = pA[ot * 16 + (q << 2) + 2];
      const float a3 = pA[ot * 16 + (q << 2) + 3];
      #pragma unroll
      for (int pg = 0; pg < 4; ++pg) {
        const float v0 = acc[oi][pg][0], v1 = acc[oi][pg][1];
        const float v2 = acc[oi][pg][2], v3 = acc[oi][pg][3];
        uint2 st;
        st.x = pack2bf(v0 > 0.f ? v0 : a0 * v0, v1 > 0.f ? v1 : a1 * v1);
        st.y = pack2bf(v2 > 0.f ? v2 : a2 * v2, v3 > 0.f ? v3 : a3 * v3);
        const int n = (b << 14) + hy * W + hx0 + pg * 16 + m16;
        *(uint2*)(outh + (size_t)n * C + ot * 16 + (q << 2)) = st;
      }
    } else {
      #pragma unroll
      for (int rg = 0; rg < 4; ++rg) {
        const int o = ot * 16 + (q << 2) + rg;
        const float s  = pA[o] * rsqrtf(pV[o] + 1e-5f);
        const float sh = pB[o] - pM[o] * s;
        #pragma unroll
        for (int pg = 0; pg < 4; ++pg) {
          const size_t oi2 = (((size_t)(b * C + o)) << 14) + hy * W + hx0 + pg * 16 + m16;
          outf[oi2] = acc[oi][pg][rg] * s + sh + resid[oi2];
        }
      }
    }
  }
}

// NCHW fp32 -> NHWC bf16, LDS-tiled (coalesced loads AND stores)
__global__ __launch_bounds__(256, 4)
void xcvt3(const float* __restrict__ x, unsigned short* __restrict__ xb)
{
  __shared__ unsigned tile[64 * 69];
  const int b   = blockIdx.y;
  const int p0  = blockIdx.x * 64;
  const int tid = threadIdx.x;
  const int pl  = tid & 63;
  const int cg  = tid >> 6;
  const float* __restrict__ xp = x + (((size_t)(b * C) + cg * 32) << 14) + p0 + pl;
  #pragma unroll
  for (int j = 0; j < 16; ++j) {
    const float a = xp[(size_t)(2 * j) << 14];
    const float c = xp[(size_t)(2 * j + 1) << 14];
    tile[pl * 69 + cg * 16 + j] = pack2bf(a, c);
  }
  __syncthreads();
  const int pl2 = tid >> 2;
  const int cq  = tid & 3;
  unsigned* dst = (unsigned*)(xb + (((size_t)(b << 14)) + p0 + pl2) * C + cq * 32);
  #pragma unroll
  for (int k = 0; k < 16; k += 4) {
    uint4 v;
    v.x = tile[pl2 * 69 + cq * 16 + k];
    v.y = tile[pl2 * 69 + cq * 16 + k + 1];
    v.z = tile[pl2 * 69 + cq * 16 + k + 2];
    v.w = tile[pl2 * 69 + cq * 16 + k + 3];
    *(uint4*)(dst + k) = v;
  }
}

// Swizzled weights, tap-major chunks: wS[((ch*NT+ot)*64+lane)*8+j] =
// w[o=ot*16+(lane&15)][c=(ch&3)*32+(lane>>4)*8+j][tap=ch>>2] (ch<36);
// ch==36: BN-shift col (kj=(lane>>4)*8+j < 9), layer-1 only.
__global__ void prep5(const float* __restrict__ w1, const float* __restrict__ w2,
                      const float* __restrict__ ow1, const float* __restrict__ mw1,
                      const float* __restrict__ ob1, const float* __restrict__ mb1,
                      const float* __restrict__ ow2, const float* __restrict__ mw2,
                      const float* __restrict__ ob2, const float* __restrict__ mb2,
                      const float* __restrict__ g, const float* __restrict__ bb,
                      const float* __restrict__ m, const float* __restrict__ v,
                      unsigned short* __restrict__ wb1, unsigned short* __restrict__ wb2,
                      unsigned short* __restrict__ wom1, unsigned short* __restrict__ wom2,
                      float* __restrict__ bias1, float* __restrict__ bias2)
{
  const int i = blockIdx.x * 256 + threadIdx.x;
  if (i < 128 * KT2) {              // deform, NT=8
    const int j = i & 7, lane = (i >> 3) & 63, ot = (i >> 9) & 7, ch = i >> 12;
    const int o = ot * 16 + (lane & 15);
    const int qj = ((lane >> 4) << 3) + j;
    unsigned short v1 = 0, v2 = 0;
    if (ch < 36) {
      const int tap = ch >> 2;
      const int c   = ((ch & 3) << 5) + qj;
      const float s = g[c] * rsqrtf(v[c] + 1e-5f);
      v1 = f2bf(w1[(size_t)(o * 128 + c) * 9 + tap] * s);
      v2 = f2bf(w2[(size_t)(o * 128 + c) * 9 + tap]);
    } else if (qj < KK) {
      float acc = 0.f;
      for (int c = 0; c < 128; ++c) {
        const float s  = g[c] * rsqrtf(v[c] + 1e-5f);
        const float sh = bb[c] - m[c] * s;
        acc += w1[(size_t)(o * 128 + c) * 9 + qj] * sh;
      }
      v1 = f2bf(acc);
    }
    wb1[i] = v1; wb2[i] = v2;
  }
  if (i < 32 * KT2) {               // offset/mask, NT=2
    const int j = i & 7, lane = (i >> 3) & 63, ot = (i >> 9) & 1, ch = i >> 10;
    const int o = ot * 16 + (lane & 15);
    const int qj = ((lane >> 4) << 3) + j;
    unsigned short v1 = 0, v2 = 0;
    if (ch < 36) {
      const int tap = ch >> 2;
      const int c   = ((ch & 3) << 5) + qj;
      const float s = g[c] * rsqrtf(v[c] + 1e-5f);
      if (o < 18) {
        v1 = f2bf(ow1[(size_t)(o * 128 + c) * 9 + tap] * s);
        v2 = f2bf(ow2[(size_t)(o * 128 + c) * 9 + tap]);
      } else if (o < 27) {
        v1 = f2bf(mw1[(size_t)((o - 18) * 128 + c) * 9 + tap] * s);
        v2 = f2bf(mw2[(size_t)((o - 18) * 128 + c) * 9 + tap]);
      }
    } else if (qj < KK && o < 27) {
      const float* wsrc = (o < 18) ? ow1 + (size_t)o * 1152
                                   : mw1 + (size_t)(o - 18) * 1152;
      float acc = 0.f;
      for (int c = 0; c < 128; ++c) {
        const float s  = g[c] * rsqrtf(v[c] + 1e-5f);
        const float sh = bb[c] - m[c] * s;
        acc += wsrc[(size_t)c * 9 + qj] * sh;
      }
      v1 = f2bf(acc);
    }
    wom1[i] = v1; wom2[i] = v2;
  }
  if (i < 32) {
    float b1 = 0.f, b2 = 0.f;
    if (i < 18)      { b1 = ob1[i];      b2 = ob2[i]; }
    else if (i < 27) { b1 = mb1[i - 18]; b2 = mb2[i - 18]; }
    bias1[i] = b1; bias2[i] = b2;
  }
}

extern "C" void kernel_launch(void* const* d_in, const int* in_sizes, int n_in,
                              void* d_out, int out_size, void* d_ws, size_t ws_size,
                              hipStream_t stream)
{
  const float* x     = (const float*)d_in[0];
  const float* bn1g  = (const float*)d_in[1];
  const float* bn1b  = (const float*)d_in[2];
  const float* bn1m  = (const float*)d_in[3];
  const float* bn1v  = (const float*)d_in[4];
  const float* ow1   = (const float*)d_in[5];
  const float* ob1   = (const float*)d_in[6];
  const float* mw1   = (const float*)d_in[7];
  const float* mb1   = (const float*)d_in[8];
  const float* w1    = (const float*)d_in[9];
  const float* alpha = (const float*)d_in[10];
  const float* ow2   = (const float*)d_in[11];
  const float* ob2   = (const float*)d_in[12];
  const float* mw2   = (const float*)d_in[13];
  const float* mb2   = (const float*)d_in[14];
  const float* w2    = (const float*)d_in[15];
  const float* bn2g  = (const float*)d_in[16];
  const float* bn2b  = (const float*)d_in[17];
  const float* bn2m  = (const float*)d_in[18];
  const float* bn2v  = (const float*)d_in[19];
  float* out = (float*)d_out;

  char* wsp = (char*)d_ws;
  unsigned short* xbf  = (unsigned short*)(wsp);             // NHWC bf16
  unsigned short* r2bf = (unsigned short*)(wsp + 16777216);  // NHWC bf16
  unsigned short* wb1  = (unsigned short*)(wsp + 40632320);  // 303104
  unsigned short* wb2  = (unsigned short*)(wsp + 40935424);  // 303104
  unsigned short* wom1 = (unsigned short*)(wsp + 41238528);  // 75776
  unsigned short* wom2 = (unsigned short*)(wsp + 41314304);  // 75776
  float* bias1 = (float*)(wsp + 41390080);
  float* bias2 = (float*)(wsp + 41390208);

  xcvt3<<<dim3(256, 4), 256, 0, stream>>>(x, xbf);
  prep5<<<(128 * KT2 + 255) / 256, 256, 0, stream>>>(
      w1, w2, ow1, mw1, ob1, mb1, ow2, mw2, ob2, mb2,
      bn1g, bn1b, bn1m, bn1v, wb1, wb2, wom1, wom2, bias1, bias2);

  fusedL<1><<<1024, 256, 0, stream>>>(xbf, wom1, wb1, bias1, alpha,
      nullptr, nullptr, nullptr, nullptr, r2bf, nullptr);
  fusedL<2><<<1024, 256, 0, stream>>>(r2bf, wom2, wb2, bias2, bn2g,
      bn2b, bn2m, bn2v, x, nullptr, out);
}